// Round 2
// baseline (323.022 us; speedup 1.0000x reference)
//
#include <hip/hip_runtime.h>
#include <hip/hip_bf16.h>
#include <stdint.h>

#define N_TOTAL 40000
#define NROW    20000
#define D       512
#define NSAMP   25
#define KDIM    1024   // 2*D
#define BM      128

typedef __bf16 bf16x8 __attribute__((ext_vector_type(8)));
typedef float  f32x4  __attribute__((ext_vector_type(4)));

__device__ inline float bf2f(unsigned short u) {
  union { uint32_t u; float f; } cv; cv.u = ((uint32_t)u) << 16; return cv.f;
}
__device__ inline unsigned short f2bf(float f) {
  union { float f; uint32_t u; } cv; cv.f = f;
  uint32_t u = cv.u;
  uint32_t r = (u + 0x7fffu + ((u >> 16) & 1u)) >> 16;  // RNE
  return (unsigned short)r;
}

__device__ inline void gload_lds16(const void* gsrc, void* ldst) {
  __builtin_amdgcn_global_load_lds(
      (const __attribute__((address_space(1))) uint32_t*)gsrc,
      (__attribute__((address_space(3))) uint32_t*)ldst,
      16, 0, 0);
}

// K0: convert features (f32->bf16) and W (f32->bf16)
__global__ void convert_kernel(const float* __restrict__ feat,
                               const float* __restrict__ W,
                               unsigned short* __restrict__ fbf,
                               unsigned short* __restrict__ wbf) {
  const int NF = N_TOTAL * D;      // 20,480,000
  const int NW = D * KDIM;         // 524,288
  const int total4 = (NF + NW) >> 2;
  for (int i = blockIdx.x * blockDim.x + threadIdx.x; i < total4;
       i += gridDim.x * blockDim.x) {
    int e = i << 2;
    float4 v;
    unsigned short* dst;
    if (e < NF) { v = *(const float4*)(feat + e); dst = fbf + e; }
    else        { int e2 = e - NF; v = *(const float4*)(W + e2); dst = wbf + e2; }
    ushort4 o;
    o.x = f2bf(v.x); o.y = f2bf(v.y); o.z = f2bf(v.z); o.w = f2bf(v.w);
    *(ushort4*)dst = o;
  }
}

// K1: gather self row + mean of 25 neighbor rows -> hcat bf16 [NROW][1024]
// All 25 loads issued before the accumulate chain (MLP); indices scalarized.
__launch_bounds__(256, 3)
__global__ void gather_kernel(const unsigned short* __restrict__ fbf,
                              const int* __restrict__ self_idx,
                              const int* __restrict__ neigh_idx,
                              unsigned short* __restrict__ hcat) {
  const int wid = threadIdx.x >> 6;
  const int lane = threadIdx.x & 63;
  const int n = blockIdx.x * 4 + wid;
  if (n >= NROW) return;
  const int col8 = lane * 8;   // 8 bf16 per lane covers 512 cols

  int si = __builtin_amdgcn_readfirstlane(self_idx[n]);
  uint4 sv = *(const uint4*)(fbf + (long)si * D + col8);
  *(uint4*)(hcat + (long)n * KDIM + col8) = sv;

  int idx[NSAMP];
#pragma unroll
  for (int s = 0; s < NSAMP; ++s)
    idx[s] = __builtin_amdgcn_readfirstlane(neigh_idx[n * NSAMP + s]);

  uint4 v[NSAMP];
#pragma unroll
  for (int s = 0; s < NSAMP; ++s)
    v[s] = *(const uint4*)(fbf + (long)idx[s] * D + col8);

  float acc[8];
#pragma unroll
  for (int j = 0; j < 8; ++j) acc[j] = 0.f;
#pragma unroll
  for (int s = 0; s < NSAMP; ++s) {
    const unsigned short* u = (const unsigned short*)&v[s];
#pragma unroll
    for (int j = 0; j < 8; ++j) acc[j] += bf2f(u[j]);
  }
  unsigned short ob[8];
#pragma unroll
  for (int j = 0; j < 8; ++j) ob[j] = f2bf(acc[j] * (1.0f / NSAMP));
  *(uint4*)(hcat + (long)n * KDIM + D + col8) = *(uint4*)ob;
}

// K2: h = relu(hcat @ W^T + b), BM=128 x BN=512 (full width), BK=32, 8 waves.
// Fused BN column-stat accumulation in the epilogue.
// LDS (k-chunk-major): A [koff][128 rows][8], B [koff][512 rows][8]
__launch_bounds__(512, 2)
__global__ void gemm_kernel(const unsigned short* __restrict__ hcat,
                            const unsigned short* __restrict__ wbf,
                            const float* __restrict__ bias,
                            float* __restrict__ h,
                            float* __restrict__ csum,
                            float* __restrict__ csq) {
  __shared__ unsigned short ldsA[4096];    // 8 KB
  __shared__ unsigned short ldsB[16384];   // 32 KB
  const int tid = threadIdx.x;
  const int lane = tid & 63, wid = tid >> 6;
  const int mb = blockIdx.x;
  const int wr = wid >> 2, wc = wid & 3;   // wave tile: rows [wr*64,+64), cols [wc*128,+128)

  // A staging: wave w stages k-plane (w>>1), rows (w&1)*64 + lane
  const int aplane = wid >> 1;
  const int arow_l = (wid & 1) * 64 + lane;
  int rowA = mb * BM + arow_l;
  if (rowA > NROW - 1) rowA = NROW - 1;     // clamp; excluded from stats/store
  const unsigned short* gA = hcat + (long)rowA * KDIM + aplane * 8;
  unsigned short* dA = &ldsA[wid * 512];    // wave-uniform base; HW adds lane*16B
  // B staging: row tid, 4 k-planes
  const unsigned short* gB = wbf + (long)tid * KDIM;

  f32x4 acc[4][8];
#pragma unroll
  for (int i = 0; i < 4; ++i)
#pragma unroll
    for (int j = 0; j < 8; ++j) acc[i][j] = (f32x4){0.f, 0.f, 0.f, 0.f};

  const int koff = lane >> 4;
  const int r16 = lane & 15;

  for (int kt = 0; kt < KDIM; kt += 32) {
    gload_lds16(gA + kt, dA);
    gload_lds16(gB + kt,      &ldsB[wid * 512]);
    gload_lds16(gB + kt + 8,  &ldsB[4096 + wid * 512]);
    gload_lds16(gB + kt + 16, &ldsB[8192 + wid * 512]);
    gload_lds16(gB + kt + 24, &ldsB[12288 + wid * 512]);
    __syncthreads();

    bf16x8 af[4], bfr[8];
#pragma unroll
    for (int mf = 0; mf < 4; ++mf)
      af[mf] = *(const bf16x8*)&ldsA[koff * 1024 + (wr * 64 + mf * 16 + r16) * 8];
#pragma unroll
    for (int nf = 0; nf < 8; ++nf)
      bfr[nf] = *(const bf16x8*)&ldsB[koff * 4096 + (wc * 128 + nf * 16 + r16) * 8];
#pragma unroll
    for (int mf = 0; mf < 4; ++mf)
#pragma unroll
      for (int nf = 0; nf < 8; ++nf)
        acc[mf][nf] = __builtin_amdgcn_mfma_f32_16x16x32_bf16(
            af[mf], bfr[nf], acc[mf][nf], 0, 0, 0);
    __syncthreads();
  }

  // epilogue: C/D layout col=lane&15, row=(lane>>4)*4+reg; fused BN stats
  const int rgrp = lane >> 4;
#pragma unroll
  for (int nf = 0; nf < 8; ++nf) {
    const int col = wc * 128 + nf * 16 + r16;
    const float bv = bias[col];
    float s = 0.f, q = 0.f;
#pragma unroll
    for (int mf = 0; mf < 4; ++mf) {
#pragma unroll
      for (int r = 0; r < 4; ++r) {
        const int m = mb * BM + wr * 64 + mf * 16 + rgrp * 4 + r;
        float v = acc[mf][nf][r] + bv;
        v = fmaxf(v, 0.f);
        if (m < NROW) {
          h[(long)m * D + col] = v;
          s += v;
          q += v * v;
        }
      }
    }
    s += __shfl_xor(s, 16); s += __shfl_xor(s, 32);
    q += __shfl_xor(q, 16); q += __shfl_xor(q, 32);
    if (rgrp == 0) {
      atomicAdd(&csum[col], s);
      atomicAdd(&csq[col], q);
    }
  }
}

// K3: BN apply + row L2 normalize; wave-per-row, hoisted column params
__launch_bounds__(256)
__global__ void finalize_kernel(const float* __restrict__ h,
                                const float* __restrict__ csum,
                                const float* __restrict__ csq,
                                const float* __restrict__ gamma,
                                const float* __restrict__ beta,
                                float* __restrict__ out) {
  const int lane = threadIdx.x & 63, wid = threadIdx.x >> 6;
  const int c0 = lane * 8;

  float mu[8], rs[8], g[8], be[8];
#pragma unroll
  for (int j = 0; j < 8; ++j) {
    const int c = c0 + j;
    const float m = csum[c] * (1.0f / NROW);
    float var = csq[c] * (1.0f / NROW) - m * m;
    var = fmaxf(var, 0.f);
    mu[j] = m;
    rs[j] = rsqrtf(var + 1e-5f) * gamma[c];
    g[j]  = rs[j];
    be[j] = beta[c];
  }

  for (int r = blockIdx.x * 4 + wid; r < NROW; r += gridDim.x * 4) {
    const float* hp = h + (long)r * D + c0;
    float4 x0 = *(const float4*)(hp);
    float4 x1 = *(const float4*)(hp + 4);
    float y[8];
    y[0] = (x0.x - mu[0]) * g[0] + be[0];
    y[1] = (x0.y - mu[1]) * g[1] + be[1];
    y[2] = (x0.z - mu[2]) * g[2] + be[2];
    y[3] = (x0.w - mu[3]) * g[3] + be[3];
    y[4] = (x1.x - mu[4]) * g[4] + be[4];
    y[5] = (x1.y - mu[5]) * g[5] + be[5];
    y[6] = (x1.z - mu[6]) * g[6] + be[6];
    y[7] = (x1.w - mu[7]) * g[7] + be[7];
    float ss = 0.f;
#pragma unroll
    for (int j = 0; j < 8; ++j) ss += y[j] * y[j];
#pragma unroll
    for (int off = 32; off > 0; off >>= 1) ss += __shfl_xor(ss, off);
    const float sc = 1.0f / (sqrtf(ss) + 1e-6f);
    float4 o0, o1;
    o0.x = y[0] * sc; o0.y = y[1] * sc; o0.z = y[2] * sc; o0.w = y[3] * sc;
    o1.x = y[4] * sc; o1.y = y[5] * sc; o1.z = y[6] * sc; o1.w = y[7] * sc;
    float* op = out + (long)r * D + c0;
    *(float4*)(op) = o0;
    *(float4*)(op + 4) = o1;
  }
}

extern "C" void kernel_launch(void* const* d_in, const int* in_sizes, int n_in,
                              void* d_out, int out_size, void* d_ws, size_t ws_size,
                              hipStream_t stream) {
  const float* feat  = (const float*)d_in[0];
  const float* W     = (const float*)d_in[1];
  const float* bias  = (const float*)d_in[2];
  const float* gamma = (const float*)d_in[3];
  const float* beta  = (const float*)d_in[4];
  const int* self_idx = (const int*)d_in[5];
  const int* neigh    = (const int*)d_in[6];
  float* out = (float*)d_out;

  char* ws = (char*)d_ws;
  unsigned short* fbf  = (unsigned short*)(ws);                    // 40,960,000 B
  unsigned short* wbf  = (unsigned short*)(ws + 40960000);         //  1,048,576 B
  unsigned short* hcat = (unsigned short*)(ws + 42008576);         // 40,960,000 B
  float* h    = (float*)(ws + 82968576);                           // 40,960,000 B
  float* csum = (float*)(ws + 123928576);                          // 2048 B
  float* csq  = (float*)(ws + 123930624);                          // 2048 B

  hipMemsetAsync(csum, 0, 4096, stream);
  convert_kernel<<<2048, 256, 0, stream>>>(feat, W, fbf, wbf);
  gather_kernel<<<(NROW + 3) / 4, 256, 0, stream>>>(fbf, self_idx, neigh, hcat);
  gemm_kernel<<<(NROW + BM - 1) / BM, 512, 0, stream>>>(hcat, wbf, bias, h, csum, csq);
  finalize_kernel<<<1250, 256, 0, stream>>>(h, csum, csq, gamma, beta, out);
}